// Round 1
// baseline (199.420 us; speedup 1.0000x reference)
//
#include <hip/hip_runtime.h>
#include <math.h>

// CriterionLSCos: MSE between 8-neighbor cosine-similarity maps of two
// [B=16, C=19, H=256, W=256] fp32 tensors.
//
// Key identity: neighbor self-norm aa(y+dy,x+dx) == center norm xx at that
// pixel, so we compute one inverse-norm per tile pixel instead of 8 per
// center. Single fused kernel: channel-loop LDS tile (center+halo), register
// accumulation of 8 dots per input, per-pixel rsqrt shared via LDS, squared
// diff reduced block-wide -> double atomicAdd -> finalize kernel divides.

constexpr int BATCH = 16;
constexpr int CH = 19;
constexpr int H = 256;
constexpr int W = 256;

constexpr int TX = 64;          // centers per block, x
constexpr int TY = 8;           // centers per block, y
constexpr int TW = TX + 2;      // 66 (tile width incl. halo)
constexpr int THH = TY + 2;     // 10 (tile height incl. halo)
constexpr int TILE = TW * THH;  // 660
constexpr int NTHREADS = TX * TY;  // 512

__global__ __launch_bounds__(NTHREADS)
void cosmap_mse_kernel(const float* __restrict__ preds,
                       const float* __restrict__ soft,
                       double* __restrict__ acc) {
  __shared__ float sp[TILE];   // preds channel tile
  __shared__ float ss[TILE];   // soft channel tile
  __shared__ float rnp[TILE];  // preds inverse norms
  __shared__ float rns[TILE];  // soft inverse norms

  const int tx = threadIdx.x;
  const int ty = threadIdx.y;
  const int tid = ty * TX + tx;
  const int b = blockIdx.z;
  const int x0 = 1 + blockIdx.x * TX;   // first center x of this tile
  const int y0 = 1 + blockIdx.y * TY;   // first center y of this tile

  // Each thread owns <=2 tile slots (660 / 512). Precompute coords once.
  const int idx0 = tid;
  const bool has2 = (tid + NTHREADS) < TILE;
  const int idx1 = has2 ? tid + NTHREADS : tid;

  auto goff = [&](int idx) -> int {
    int j = idx / TW;
    int i = idx - j * TW;
    int gy = y0 - 1 + j; gy = gy > H - 1 ? H - 1 : gy;  // clamp (only
    int gx = x0 - 1 + i; gx = gx > W - 1 ? W - 1 : gx;  // invalid centers use it)
    return gy * W + gx;
  };
  const int off0 = goff(idx0);
  const int off1 = goff(idx1);

  const size_t base = (size_t)b * CH * H * W;
  const float* pp = preds + base;
  const float* ps = soft + base;

  float dotp[8], dots[8];
#pragma unroll
  for (int k = 0; k < 8; ++k) { dotp[k] = 0.f; dots[k] = 0.f; }
  float xxp0 = 0.f, xxs0 = 0.f, xxp1 = 0.f, xxs1 = 0.f;

  const int ci = (ty + 1) * TW + (tx + 1);

  for (int c = 0; c < CH; ++c) {
    const size_t cb = (size_t)c * (H * W);
    // stage channel tile (coalesced: consecutive tid -> consecutive gx)
    float vp0 = pp[cb + off0];
    float vs0 = ps[cb + off0];
    float vp1 = pp[cb + off1];
    float vs1 = ps[cb + off1];
    sp[idx0] = vp0; ss[idx0] = vs0;
    if (has2) { sp[idx1] = vp1; ss[idx1] = vs1; }
    // self-norm accumulation in registers (thread owns its slots)
    xxp0 = fmaf(vp0, vp0, xxp0); xxs0 = fmaf(vs0, vs0, xxs0);
    xxp1 = fmaf(vp1, vp1, xxp1); xxs1 = fmaf(vs1, vs1, xxs1);
    __syncthreads();

    const float cp = sp[ci];
    const float cs = ss[ci];
    constexpr int offs[8] = {-TW - 1, -TW, -TW + 1, -1, 1, TW - 1, TW, TW + 1};
#pragma unroll
    for (int k = 0; k < 8; ++k) {
      dotp[k] = fmaf(cp, sp[ci + offs[k]], dotp[k]);
      dots[k] = fmaf(cs, ss[ci + offs[k]], dots[k]);
    }
    __syncthreads();
  }

  // publish inverse norms (one rsqrt per tile pixel, not 9 per center)
  rnp[idx0] = 1.0f / sqrtf(xxp0);
  rns[idx0] = 1.0f / sqrtf(xxs0);
  if (has2) {
    rnp[idx1] = 1.0f / sqrtf(xxp1);
    rns[idx1] = 1.0f / sqrtf(xxs1);
  }
  __syncthreads();

  float local = 0.f;
  const int px = x0 + tx;
  const int py = y0 + ty;
  if (px < W - 1 && py < H - 1) {  // valid centers: 1..254
    const float rp = rnp[ci];
    const float rs = rns[ci];
    constexpr int offs[8] = {-TW - 1, -TW, -TW + 1, -1, 1, TW - 1, TW, TW + 1};
#pragma unroll
    for (int k = 0; k < 8; ++k) {
      float mp = dotp[k] * rp * rnp[ci + offs[k]];
      float ms = dots[k] * rs * rns[ci + offs[k]];
      float d = mp - ms;
      local = fmaf(d, d, local);
    }
  }

  // block reduction: wave shuffle then cross-wave LDS
#pragma unroll
  for (int o = 32; o > 0; o >>= 1) local += __shfl_down(local, o, 64);
  __shared__ float wsum[NTHREADS / 64];
  const int wid = tid >> 6;
  const int lane = tid & 63;
  if (lane == 0) wsum[wid] = local;
  __syncthreads();
  if (tid == 0) {
    float s = 0.f;
#pragma unroll
    for (int w = 0; w < NTHREADS / 64; ++w) s += wsum[w];
    atomicAdd(acc, (double)s);
  }
}

__global__ void finalize_kernel(const double* __restrict__ acc,
                                float* __restrict__ out) {
  constexpr double cnt = (double)BATCH * 8.0 * (H - 2) * (W - 2);
  out[0] = (float)(acc[0] / cnt);
}

extern "C" void kernel_launch(void* const* d_in, const int* in_sizes, int n_in,
                              void* d_out, int out_size, void* d_ws, size_t ws_size,
                              hipStream_t stream) {
  const float* preds = (const float*)d_in[0];
  const float* soft = (const float*)d_in[1];
  double* acc = (double*)d_ws;

  // d_ws is poisoned 0xAA before every launch -> zero the accumulator
  hipMemsetAsync(d_ws, 0, sizeof(double), stream);

  dim3 block(TX, TY);
  dim3 grid((W - 2 + TX - 1) / TX, (H - 2 + TY - 1) / TY, BATCH);
  cosmap_mse_kernel<<<grid, block, 0, stream>>>(preds, soft, acc);
  finalize_kernel<<<1, 1, 0, stream>>>(acc, (float*)d_out);
}

// Round 2
// 183.461 us; speedup vs baseline: 1.0870x; 1.0870x over previous
//
#include <hip/hip_runtime.h>
#include <math.h>

// CriterionLSCos: MSE between 8-neighbor cosine-similarity maps of two
// [16,19,256,256] fp32 tensors.
//
// R1 changes vs R0 (81.5us, latency-bound: HBM 21%, VALU 22%):
//  - software-pipelined channel loop: prefetch ch+1 into regs before the
//    single barrier of ch; double-buffered LDS (19 barriers, was 38)
//  - 2 centers/thread, float2 (ds_read_b64) windows: 6 b64/tensor/channel
//    feed both centers' stencils (was 18 scalar reads per center)
//  - inverse-norm arrays alias LDS buffer 1 (21KB/block total)

constexpr int BATCH = 16, CH = 19, H = 256, W = 256;
constexpr int BXT = 64, BYT = 8, NT = BXT * BYT;  // 512 threads
constexpr int CX = 128, CY = 8;                    // centers per block
constexpr int TW2 = 66;                            // float2 per tile row (132 floats)
constexpr int TH = 10;                             // tile rows
constexpr int NP = TW2 * TH;                       // 660 float2 slots

__global__ __launch_bounds__(NT)
void cosmap_mse_kernel(const float* __restrict__ preds,
                       const float* __restrict__ soft,
                       double* __restrict__ acc_out) {
  __shared__ float2 sp[2][NP];   // preds tile, double-buffered
  __shared__ float2 ss[2][NP];   // soft tile
  __shared__ float wsum[NT / 64];

  const int tx = threadIdx.x, ty = threadIdx.y;
  const int tid = ty * BXT + tx;
  const int x0 = 1 + blockIdx.x * CX;
  const int y0 = 1 + blockIdx.y * CY;

  // --- staging ownership: pair p <-> float2 slot p (tile cols 2i2, 2i2+1)
  const int p0 = tid;
  const bool has2 = tid < (NP - NT);  // 148 threads own a second slot
  const int p1 = has2 ? tid + NT : tid;

  bool ov0 = false, ov1 = false;
  int e0, e1;
  {
    int j = p0 / TW2, i2 = p0 - j * TW2;
    int gy = y0 - 1 + j; gy = gy > H - 1 ? H - 1 : gy;
    int gs = x0 - 1 + 2 * i2;
    ov0 = gs >= W - 1;               // both cols clamp to 255
    e0 = gy * W + (ov0 ? W - 2 : gs);
  }
  {
    int j = p1 / TW2, i2 = p1 - j * TW2;
    int gy = y0 - 1 + j; gy = gy > H - 1 ? H - 1 : gy;
    int gs = x0 - 1 + 2 * i2;
    ov1 = gs >= W - 1;
    e1 = gy * W + (ov1 ? W - 2 : gs);
  }

  const size_t base = (size_t)blockIdx.z * CH * H * W;
  const float2* pp = (const float2*)(preds + base);
  const float2* qq = (const float2*)(soft + base);
  const int f0 = e0 >> 1, f1 = e1 >> 1;
  constexpr int CS2 = H * W / 2;  // channel stride in float2

  // prefetch channel 0
  float2 vp0 = pp[f0], vq0 = qq[f0], vp1 = pp[f1], vq1 = qq[f1];

  float a[8], bb[8], c[8], d[8];   // dot accs: preds c0/c1, soft c0/c1
#pragma unroll
  for (int k = 0; k < 8; ++k) { a[k] = 0.f; bb[k] = 0.f; c[k] = 0.f; d[k] = 0.f; }
  float2 np0 = {0.f, 0.f}, np1 = {0.f, 0.f}, nq0 = {0.f, 0.f}, nq1 = {0.f, 0.f};

  const int r0 = ty * TW2 + tx;    // window: rows r0, r0+TW2, r0+2*TW2; +0,+1

  for (int ch = 0; ch < CH; ++ch) {
    float2* SP = sp[ch & 1];
    float2* SS = ss[ch & 1];
    // clamp-fix, stage, accumulate self-norms
    float2 wp0 = vp0; if (ov0) wp0.x = wp0.y;
    float2 wq0 = vq0; if (ov0) wq0.x = wq0.y;
    float2 wp1 = vp1; if (ov1) wp1.x = wp1.y;
    float2 wq1 = vq1; if (ov1) wq1.x = wq1.y;
    SP[p0] = wp0; SS[p0] = wq0;
    if (has2) { SP[p1] = wp1; SS[p1] = wq1; }
    np0.x = fmaf(wp0.x, wp0.x, np0.x); np0.y = fmaf(wp0.y, wp0.y, np0.y);
    nq0.x = fmaf(wq0.x, wq0.x, nq0.x); nq0.y = fmaf(wq0.y, wq0.y, nq0.y);
    if (has2) {
      np1.x = fmaf(wp1.x, wp1.x, np1.x); np1.y = fmaf(wp1.y, wp1.y, np1.y);
      nq1.x = fmaf(wq1.x, wq1.x, nq1.x); nq1.y = fmaf(wq1.y, wq1.y, nq1.y);
    }
    // prefetch next channel (in flight across barrier + compute)
    if (ch + 1 < CH) {
      const int o = (ch + 1) * CS2;
      vp0 = pp[f0 + o]; vq0 = qq[f0 + o];
      vp1 = pp[f1 + o]; vq1 = qq[f1 + o];
    }
    __syncthreads();  // single barrier/iter: writes to buf[ch&1] visible;
                      // next iter writes buf[ch+1&1], last read pre-barrier.
    {
      float2 u0 = SP[r0],           u1 = SP[r0 + 1];
      float2 m0 = SP[r0 + TW2],     m1 = SP[r0 + TW2 + 1];
      float2 l0 = SP[r0 + 2 * TW2], l1 = SP[r0 + 2 * TW2 + 1];
      float c0 = m0.y, c1 = m1.x;
      a[0] = fmaf(c0, u0.x, a[0]); a[1] = fmaf(c0, u0.y, a[1]); a[2] = fmaf(c0, u1.x, a[2]);
      a[3] = fmaf(c0, m0.x, a[3]); a[4] = fmaf(c0, m1.x, a[4]);
      a[5] = fmaf(c0, l0.x, a[5]); a[6] = fmaf(c0, l0.y, a[6]); a[7] = fmaf(c0, l1.x, a[7]);
      bb[0] = fmaf(c1, u0.y, bb[0]); bb[1] = fmaf(c1, u1.x, bb[1]); bb[2] = fmaf(c1, u1.y, bb[2]);
      bb[3] = fmaf(c1, m0.y, bb[3]); bb[4] = fmaf(c1, m1.y, bb[4]);
      bb[5] = fmaf(c1, l0.y, bb[5]); bb[6] = fmaf(c1, l1.x, bb[6]); bb[7] = fmaf(c1, l1.y, bb[7]);
    }
    {
      float2 u0 = SS[r0],           u1 = SS[r0 + 1];
      float2 m0 = SS[r0 + TW2],     m1 = SS[r0 + TW2 + 1];
      float2 l0 = SS[r0 + 2 * TW2], l1 = SS[r0 + 2 * TW2 + 1];
      float c0 = m0.y, c1 = m1.x;
      c[0] = fmaf(c0, u0.x, c[0]); c[1] = fmaf(c0, u0.y, c[1]); c[2] = fmaf(c0, u1.x, c[2]);
      c[3] = fmaf(c0, m0.x, c[3]); c[4] = fmaf(c0, m1.x, c[4]);
      c[5] = fmaf(c0, l0.x, c[5]); c[6] = fmaf(c0, l0.y, c[6]); c[7] = fmaf(c0, l1.x, c[7]);
      d[0] = fmaf(c1, u0.y, d[0]); d[1] = fmaf(c1, u1.x, d[1]); d[2] = fmaf(c1, u1.y, d[2]);
      d[3] = fmaf(c1, m0.y, d[3]); d[4] = fmaf(c1, m1.y, d[4]);
      d[5] = fmaf(c1, l0.y, d[5]); d[6] = fmaf(c1, l1.x, d[6]); d[7] = fmaf(c1, l1.y, d[7]);
    }
  }

  // inverse norms -> buffer 1 (last compute read buffer 0; buf1's last
  // readers finished before the ch=18 barrier)
  {
    float2 r;
    r.x = 1.0f / sqrtf(np0.x); r.y = 1.0f / sqrtf(np0.y); sp[1][p0] = r;
    r.x = 1.0f / sqrtf(nq0.x); r.y = 1.0f / sqrtf(nq0.y); ss[1][p0] = r;
    if (has2) {
      r.x = 1.0f / sqrtf(np1.x); r.y = 1.0f / sqrtf(np1.y); sp[1][p1] = r;
      r.x = 1.0f / sqrtf(nq1.x); r.y = 1.0f / sqrtf(nq1.y); ss[1][p1] = r;
    }
  }
  __syncthreads();

  float local = 0.f;
  {
    const float2* RP = sp[1];
    const float2* RS = ss[1];
    float2 u0 = RP[r0],           u1 = RP[r0 + 1];
    float2 m0 = RP[r0 + TW2],     m1 = RP[r0 + TW2 + 1];
    float2 l0 = RP[r0 + 2 * TW2], l1 = RP[r0 + 2 * TW2 + 1];
    float2 su0 = RS[r0],           su1 = RS[r0 + 1];
    float2 sm0 = RS[r0 + TW2],     sm1 = RS[r0 + TW2 + 1];
    float2 sl0 = RS[r0 + 2 * TW2], sl1 = RS[r0 + 2 * TW2 + 1];
    float rc0 = m0.y, rc1 = m1.x, sc0 = sm0.y, sc1 = sm1.x;
    float n0p[8] = {u0.x, u0.y, u1.x, m0.x, m1.x, l0.x, l0.y, l1.x};
    float n1p[8] = {u0.y, u1.x, u1.y, m0.y, m1.y, l0.y, l1.x, l1.y};
    float n0s[8] = {su0.x, su0.y, su1.x, sm0.x, sm1.x, sl0.x, sl0.y, sl1.x};
    float n1s[8] = {su0.y, su1.x, su1.y, sm0.y, sm1.y, sl0.y, sl1.x, sl1.y};
    float acc0 = 0.f, acc1 = 0.f;
#pragma unroll
    for (int k = 0; k < 8; ++k) {
      float mp = a[k] * rc0 * n0p[k];
      float ms = c[k] * sc0 * n0s[k];
      float dd = mp - ms;
      acc0 = fmaf(dd, dd, acc0);
      float mp1 = bb[k] * rc1 * n1p[k];
      float ms1 = d[k] * sc1 * n1s[k];
      float d1v = mp1 - ms1;
      acc1 = fmaf(d1v, d1v, acc1);
    }
    const int cgx = x0 + 2 * tx, cgy = y0 + ty;
    const bool vy = cgy <= H - 2;
    local = (vy && cgx <= W - 2 ? acc0 : 0.f) + (vy && cgx + 1 <= W - 2 ? acc1 : 0.f);
  }

#pragma unroll
  for (int o = 32; o > 0; o >>= 1) local += __shfl_down(local, o, 64);
  if ((tid & 63) == 0) wsum[tid >> 6] = local;
  __syncthreads();
  if (tid == 0) {
    float s = 0.f;
#pragma unroll
    for (int w = 0; w < NT / 64; ++w) s += wsum[w];
    atomicAdd(acc_out, (double)s);
  }
}

__global__ void finalize_kernel(const double* __restrict__ acc,
                                float* __restrict__ out) {
  constexpr double cnt = (double)BATCH * 8.0 * (H - 2) * (W - 2);
  out[0] = (float)(acc[0] / cnt);
}

extern "C" void kernel_launch(void* const* d_in, const int* in_sizes, int n_in,
                              void* d_out, int out_size, void* d_ws, size_t ws_size,
                              hipStream_t stream) {
  const float* preds = (const float*)d_in[0];
  const float* soft = (const float*)d_in[1];
  double* acc = (double*)d_ws;

  hipMemsetAsync(d_ws, 0, sizeof(double), stream);  // ws is 0xAA-poisoned

  dim3 block(BXT, BYT);
  dim3 grid((W - 2 + CX - 1) / CX, (H - 2 + CY - 1) / CY, BATCH);
  cosmap_mse_kernel<<<grid, block, 0, stream>>>(preds, soft, acc);
  finalize_kernel<<<1, 1, 0, stream>>>(acc, (float*)d_out);
}